// Round 11
// baseline (148.106 us; speedup 1.0000x reference)
//
#include <hip/hip_runtime.h>
#include <math.h>

#define N_PTS 2048
#define M_PTS 128
#define INNF  256
#define H     128

#define MIN_STDC 0.30235680f   /* 0.32*1.88973/2 */
#define MAX_STDC 2.19208680f   /* 2.32*1.88973/2 */
#define PI_F     3.14159265358979f
#define LOG2E_F  1.44269504089f

static __device__ __forceinline__ float silu_f(float x) {
  return x / (1.0f + __expf(-x));
}

// ---------------------------------------------------------------------------
// K1 (unchanged): weights staged through LDS once per block. 256 blocks.
// ---------------------------------------------------------------------------
__global__ __launch_bounds__(256) void k_pre(const float* __restrict__ h,
    const float* __restrict__ W_pre, const float* __restrict__ b_pre,
    const float* __restrict__ W_down, const float* __restrict__ gw,
    float* __restrict__ hdg4) {
  __shared__ float bigW[12288];
  __shared__ float h_t[8 * INNF];
  __shared__ float hp_t[8 * H];
  int t = threadIdx.x;
  int n0 = blockIdx.x * 8;
  int lw = t & 31;
  int g  = t >> 5;
  int w0 = lw * 4;

  #pragma unroll
  for (int i = 0; i < 2; ++i) {
    int idx = t + i * 256;
    int row = idx >> 6, col = (idx & 63) << 2;
    *(float4*)&h_t[row * INNF + col] =
        *(const float4*)(h + (size_t)(n0 + row) * INNF + col);
  }

  float acc[4] = {};
  for (int kc = 0; kc < 256; kc += 64) {
    __syncthreads();
    #pragma unroll
    for (int i = 0; i < 8; ++i) {
      int idx = t + i * 256;
      *(float4*)&bigW[idx * 4] = *(const float4*)(W_pre + (size_t)kc * H + idx * 4);
    }
    __syncthreads();
    #pragma unroll 4
    for (int u4 = 0; u4 < 16; ++u4) {
      float4 hv = *(const float4*)&h_t[g * INNF + kc + u4 * 4];
      float hvv[4] = {hv.x, hv.y, hv.z, hv.w};
      #pragma unroll
      for (int uu = 0; uu < 4; ++uu) {
        float4 wv = *(const float4*)&bigW[(u4 * 4 + uu) * H + w0];
        acc[0] += hvv[uu] * wv.x; acc[1] += hvv[uu] * wv.y;
        acc[2] += hvv[uu] * wv.z; acc[3] += hvv[uu] * wv.w;
      }
    }
  }
  {
    float4 bv = *(const float4*)(b_pre + w0);
    float4 o = make_float4(silu_f(acc[0] + bv.x), silu_f(acc[1] + bv.y),
                           silu_f(acc[2] + bv.z), silu_f(acc[3] + bv.w));
    __syncthreads();
    *(float4*)&hp_t[g * H + w0] = o;
  }

  float acc2[3][4] = {};
  for (int kc = 0; kc < 128; kc += 32) {
    __syncthreads();
    #pragma unroll
    for (int i = 0; i < 12; ++i) {
      int idx = t + i * 256;
      int l = idx >> 10, r4 = idx & 1023;
      *(float4*)&bigW[idx * 4] =
          *(const float4*)(W_down + ((size_t)l * H + kc) * H + r4 * 4);
    }
    __syncthreads();
    #pragma unroll 2
    for (int u4 = 0; u4 < 8; ++u4) {
      float4 pv = *(const float4*)&hp_t[g * H + kc + u4 * 4];
      float pvv[4] = {pv.x, pv.y, pv.z, pv.w};
      #pragma unroll
      for (int uu = 0; uu < 4; ++uu) {
        int ul = u4 * 4 + uu;
        #pragma unroll
        for (int l = 0; l < 3; ++l) {
          float4 wv = *(const float4*)&bigW[(l * 32 + ul) * H + w0];
          acc2[l][0] += pvv[uu] * wv.x; acc2[l][1] += pvv[uu] * wv.y;
          acc2[l][2] += pvv[uu] * wv.z; acc2[l][3] += pvv[uu] * wv.w;
        }
      }
    }
  }

  {
    const float stp = (MAX_STDC - MIN_STDC) / 127.0f;
    const float invn1 = 0.57735026919f, invn2 = 0.44721359550f;
    int n = n0 + g;
    float gwv = gw[n];
    #pragma unroll
    for (int i = 0; i < 4; ++i) {
      int w = w0 + i;
      float s = MIN_STDC + (float)w * stp;
      float temps = 2.0f * s * s;
      float coef = (2.0f / 3.0f) / (temps * powf(PI_F * temps, 1.5f));
      float sc = gwv * coef;
      *(float4*)(hdg4 + ((size_t)n * H + w) * 4) =
          make_float4(acc2[0][i] * sc, acc2[1][i] * sc * invn1,
                      acc2[2][i] * sc * invn2, 0.0f);
    }
  }
}

// ---------------------------------------------------------------------------
// K2 (unchanged): pair loop, 2 w per lane, private 16-n subchunks,
// 2-stage LDS tree reduce. grid (32 mg, 32 s) = 1024 blocks.
// ---------------------------------------------------------------------------
__global__ __launch_bounds__(256) void k_down(const float* __restrict__ gc,
    const float* __restrict__ cc, const float* __restrict__ hdg4,
    float* __restrict__ c_part) {
  __shared__ float sh_t[3072];
  __shared__ float red[9216];
  int t = threadIdx.x;
  int m0 = blockIdx.x * 4;
  int ss = blockIdx.y;
  int n0 = ss * 64;
  int wv = t >> 6;
  int ln = t & 63;
  int w0 = ln * 2;

  {
    int n_loc = t >> 2, m_loc = t & 3;
    int n = n0 + n_loc, m = m0 + m_loc;
    float dx = gc[3*n]   - cc[3*m];
    float dy = gc[3*n+1] - cc[3*m+1];
    float dz = gc[3*n+2] - cc[3*m+2];
    float d2 = dx*dx + dy*dy + dz*dz + 3e-20f;
    float inv = rsqrtf(d2);
    float x = dx*inv, y = dy*inv, z = dz*inv;
    const float s3 = 1.73205080757f;
    float* dst = &sh_t[(size_t)t * 12];
    dst[0] = 1.0f; dst[1] = x; dst[2] = y; dst[3] = z;
    dst[4] = s3*x*z; dst[5] = s3*x*y; dst[6] = y*y - 0.5f*(x*x + z*z);
    dst[7] = s3*y*z; dst[8] = 0.5f*s3*(z*z - x*x);
    dst[9] = d2; dst[10] = 0.0f; dst[11] = 0.0f;
  }
  __syncthreads();

  const float stp = (MAX_STDC - MIN_STDC) / 127.0f;
  float sA = MIN_STDC + (float)w0 * stp;
  float sB = MIN_STDC + (float)(w0 + 1) * stp;
  float cA = -LOG2E_F / (2.0f * sA * sA);
  float cB = -LOG2E_F / (2.0f * sB * sB);

  float acc[4][9][2] = {};
  for (int j = 0; j < 16; ++j) {
    int nl = wv * 16 + j;
    const float4* hb = (const float4*)(hdg4 + ((size_t)(n0 + nl) * H + w0) * 4);
    float4 hv0 = hb[0];
    float4 hv1 = hb[1];
    const float* shb = &sh_t[(size_t)nl * 48];
    #pragma unroll
    for (int mm = 0; mm < 4; ++mm) {
      float4 q0 = *(const float4*)(shb + mm*12);
      float4 q1 = *(const float4*)(shb + mm*12 + 4);
      float4 q2 = *(const float4*)(shb + mm*12 + 8);
      float e0 = exp2f(q2.y * cA);
      float e1 = exp2f(q2.y * cB);
      float rp0 = e0 * q2.y, rp1 = e1 * q2.y;
      float a00 = hv0.x*rp0, a01 = hv0.y*rp0, a02 = hv0.z*rp0;
      float a10 = hv1.x*rp1, a11 = hv1.y*rp1, a12 = hv1.z*rp1;
      acc[mm][0][0] += a00;        acc[mm][0][1] += a10;
      acc[mm][1][0] += a01*q0.y;   acc[mm][1][1] += a11*q0.y;
      acc[mm][2][0] += a01*q0.z;   acc[mm][2][1] += a11*q0.z;
      acc[mm][3][0] += a01*q0.w;   acc[mm][3][1] += a11*q0.w;
      acc[mm][4][0] += a02*q1.x;   acc[mm][4][1] += a12*q1.x;
      acc[mm][5][0] += a02*q1.y;   acc[mm][5][1] += a12*q1.y;
      acc[mm][6][0] += a02*q1.z;   acc[mm][6][1] += a12*q1.z;
      acc[mm][7][0] += a02*q1.w;   acc[mm][7][1] += a12*q1.w;
      acc[mm][8][0] += a02*q2.x;   acc[mm][8][1] += a12*q2.x;
    }
  }

  __syncthreads();
  if (wv & 1) {
    float* dst = &red[(wv >> 1) * 4608];
    #pragma unroll
    for (int mm = 0; mm < 4; ++mm)
      #pragma unroll
      for (int li = 0; li < 9; ++li)
        *(float2*)&dst[(mm*9 + li)*128 + w0] =
            make_float2(acc[mm][li][0], acc[mm][li][1]);
  }
  __syncthreads();
  if (!(wv & 1)) {
    const float* src = &red[(wv >> 1) * 4608];
    #pragma unroll
    for (int mm = 0; mm < 4; ++mm)
      #pragma unroll
      for (int li = 0; li < 9; ++li) {
        float2 v = *(const float2*)&src[(mm*9 + li)*128 + w0];
        acc[mm][li][0] += v.x; acc[mm][li][1] += v.y;
      }
  }
  __syncthreads();
  if (wv == 2) {
    #pragma unroll
    for (int mm = 0; mm < 4; ++mm)
      #pragma unroll
      for (int li = 0; li < 9; ++li)
        *(float2*)&red[(mm*9 + li)*128 + w0] =
            make_float2(acc[mm][li][0], acc[mm][li][1]);
  }
  __syncthreads();
  if (wv == 0) {
    #pragma unroll
    for (int mm = 0; mm < 4; ++mm)
      #pragma unroll
      for (int li = 0; li < 9; ++li) {
        float2 v = *(const float2*)&red[(mm*9 + li)*128 + w0];
        float2 o = make_float2(acc[mm][li][0] + v.x, acc[mm][li][1] + v.y);
        *(float2*)&c_part[(((size_t)ss*M_PTS + m0 + mm)*9 + li)*H + w0] = o;
      }
  }
}

// ---------------------------------------------------------------------------
// K3 (unchanged): block = (m, li), grid (128, 9) = 1152 blocks, 128 threads.
// ---------------------------------------------------------------------------
__global__ __launch_bounds__(128) void k_cu(const float* __restrict__ c_part,
    const float* __restrict__ W_up, float* __restrict__ CU9) {
  __shared__ float c_lds[H];
  int t = threadIdx.x;
  int m = blockIdx.x, li = blockIdx.y;
  float v = 0.0f;
  #pragma unroll 8
  for (int s = 0; s < 32; ++s)
    v += c_part[(((size_t)s*M_PTS + m)*9 + li)*H + t];
  c_lds[t] = v;
  __syncthreads();

  int l = (li == 0) ? 0 : (li < 4 ? 1 : 2);
  const float invn[3] = {1.0f, 0.57735026919f, 0.44721359550f};
  float acc = 0.0f;
  for (int u = 0; u < H; u += 4) {
    float w0 = W_up[((size_t)l*H + u + 0)*H + t];
    float w1 = W_up[((size_t)l*H + u + 1)*H + t];
    float w2 = W_up[((size_t)l*H + u + 2)*H + t];
    float w3 = W_up[((size_t)l*H + u + 3)*H + t];
    acc += c_lds[u]*w0 + c_lds[u+1]*w1 + c_lds[u+2]*w2 + c_lds[u+3]*w3;
  }
  CU9[((size_t)m*9 + li)*H + t] = acc * invn[l];
}

// ---------------------------------------------------------------------------
// K4 v4: thread tile 8n x 8w -> 1 B LDS read per FMA (was 2).
// 128 threads, block tile 64n x 128w, split-K 16 (K=72, single chunk),
// grid (32, 16) = 512 blocks, LDS 57.6 KB -> 2 blocks/CU, 4 waves/CU.
// 64 independent accumulators provide the ILP to cover LDS latency.
// ---------------------------------------------------------------------------
__global__ __launch_bounds__(128) void k_up(const float* __restrict__ gc,
    const float* __restrict__ cc, const float* __restrict__ CU9,
    float* __restrict__ out_part) {
  __shared__ float At[72 * 72];   // [mrel*9+li][n_loc 0..63], row pad 72
  __shared__ float Bl[72 * 128];  // [k][w]
  int t = threadIdx.x;            // 0..127
  int n0 = blockIdx.x * 64;
  int ks = blockIdx.y;            // 0..15
  int wq  = t & 15;               // w0 = 8*wq
  int tgn = t >> 4;               // 0..7 -> n_loc0 = 8*tgn
  int w0 = wq * 8;
  int m0 = ks * 8;

  // stage A: 64n x 8m = 512 SH pairs, 4 per thread
  #pragma unroll
  for (int i = 0; i < 4; ++i) {
    int idx = t + i * 128;        // 0..511
    int n_loc = idx >> 3, mrel = idx & 7;
    int n = n0 + n_loc, m = m0 + mrel;
    float dx = gc[3*n]   - cc[3*m];
    float dy = gc[3*n+1] - cc[3*m+1];
    float dz = gc[3*n+2] - cc[3*m+2];
    float d2 = dx*dx + dy*dy + dz*dz + 3e-20f;
    float inv = rsqrtf(d2);
    float x = dx*inv, y = dy*inv, z = dz*inv;
    const float s3 = 1.73205080757f;
    float sh[9];
    sh[0] = 1.0f; sh[1] = x; sh[2] = y; sh[3] = z;
    sh[4] = s3*x*z; sh[5] = s3*x*y; sh[6] = y*y - 0.5f*(x*x + z*z);
    sh[7] = s3*y*z; sh[8] = 0.5f*s3*(z*z - x*x);
    #pragma unroll
    for (int li = 0; li < 9; ++li)
      At[(mrel*9 + li)*72 + n_loc] = sh[li];
  }
  // stage B: 72x128 = 2304 f4, 18 per thread
  #pragma unroll
  for (int i = 0; i < 18; ++i) {
    int idx = t + i * 128;
    *(float4*)&Bl[idx*4] = *(const float4*)(CU9 + (size_t)m0*9*H + idx*4);
  }
  __syncthreads();

  float acc[8][8] = {};
  #pragma unroll 4
  for (int k = 0; k < 72; ++k) {
    float4 a0 = *(const float4*)&At[k*72 + 8*tgn];
    float4 a1 = *(const float4*)&At[k*72 + 8*tgn + 4];
    float4 b0 = *(const float4*)&Bl[k*128 + w0];
    float4 b1 = *(const float4*)&Bl[k*128 + w0 + 4];
    float av[8] = {a0.x, a0.y, a0.z, a0.w, a1.x, a1.y, a1.z, a1.w};
    float bv[8] = {b0.x, b0.y, b0.z, b0.w, b1.x, b1.y, b1.z, b1.w};
    #pragma unroll
    for (int r = 0; r < 8; ++r)
      #pragma unroll
      for (int c = 0; c < 8; ++c)
        acc[r][c] += av[r] * bv[c];
  }
  #pragma unroll
  for (int r = 0; r < 8; ++r) {
    size_t row = (size_t)ks*N_PTS + n0 + 8*tgn + r;
    *(float4*)(out_part + row*H + w0) =
        make_float4(acc[r][0], acc[r][1], acc[r][2], acc[r][3]);
    *(float4*)(out_part + row*H + w0 + 4) =
        make_float4(acc[r][4], acc[r][5], acc[r][6], acc[r][7]);
  }
}

// ---------------------------------------------------------------------------
// K5: reduce 16 split-K partials, post-MLP + silu -> d_out.
// ---------------------------------------------------------------------------
__global__ __launch_bounds__(256) void k_post(const float* __restrict__ out_part,
    const float* __restrict__ W_post, const float* __restrict__ b_post,
    float* __restrict__ out) {
  __shared__ float op[4 * H];
  int t = threadIdx.x;
  int n0 = blockIdx.x * 4;
  int w = t & 127, nh = t >> 7;

  #pragma unroll
  for (int i = 0; i < 2; ++i) {
    int idx = t + i*256;
    int nl = idx >> 7, ww = idx & 127;
    float v = 0.0f;
    #pragma unroll
    for (int s = 0; s < 16; ++s)
      v += out_part[((size_t)s*N_PTS + n0 + nl)*H + ww];
    op[nl*H + ww] = v;
  }
  __syncthreads();

  float acc[2] = {0.0f, 0.0f};
  for (int u = 0; u < H; u += 4) {
    float4 p0 = *(const float4*)&op[(nh*2 + 0)*H + u];
    float4 p1 = *(const float4*)&op[(nh*2 + 1)*H + u];
    float w0 = W_post[(u+0)*H + w];
    float w1 = W_post[(u+1)*H + w];
    float w2 = W_post[(u+2)*H + w];
    float w3 = W_post[(u+3)*H + w];
    acc[0] += p0.x*w0 + p0.y*w1 + p0.z*w2 + p0.w*w3;
    acc[1] += p1.x*w0 + p1.y*w1 + p1.z*w2 + p1.w*w3;
  }
  float bp = b_post[w];
  out[(size_t)(n0 + nh*2 + 0)*H + w] = silu_f(acc[0] + bp);
  out[(size_t)(n0 + nh*2 + 1)*H + w] = silu_f(acc[1] + bp);
}

// ---------------------------------------------------------------------------
extern "C" void kernel_launch(void* const* d_in, const int* in_sizes, int n_in,
                              void* d_out, int out_size, void* d_ws, size_t ws_size,
                              hipStream_t stream) {
  const float* h      = (const float*)d_in[0];
  const float* gc     = (const float*)d_in[1];
  const float* cc     = (const float*)d_in[2];
  const float* gw     = (const float*)d_in[3];
  const float* W_pre  = (const float*)d_in[4];
  const float* b_pre  = (const float*)d_in[5];
  const float* W_down = (const float*)d_in[6];
  const float* W_up   = (const float*)d_in[7];
  const float* W_post = (const float*)d_in[8];
  const float* b_post = (const float*)d_in[9];

  float* ws       = (float*)d_ws;
  float* hdg4     = ws;                     // 2048*128*4   = 1,048,576 f
  float* c_part   = hdg4 + 1048576;         // 32*128*9*128 = 4,718,592 f
  float* CU9      = c_part + 4718592;       // 128*9*128    =   147,456 f
  float* out_part = c_part;                 // 16*2048*128 aliases c_part
  float* out      = (float*)d_out;

  k_pre <<<256,           256, 0, stream>>>(h, W_pre, b_pre, W_down, gw, hdg4);
  k_down<<<dim3(32,32),   256, 0, stream>>>(gc, cc, hdg4, c_part);
  k_cu  <<<dim3(128,9),   128, 0, stream>>>(c_part, W_up, CU9);
  k_up  <<<dim3(32,16),   128, 0, stream>>>(gc, cc, CU9, out_part);
  k_post<<<512,           256, 0, stream>>>(out_part, W_post, b_post, out);
}

// Round 12
// 138.606 us; speedup vs baseline: 1.0685x; 1.0685x over previous
//
#include <hip/hip_runtime.h>
#include <math.h>

#define N_PTS 2048
#define M_PTS 128
#define INNF  256
#define H     128

#define MIN_STDC 0.30235680f   /* 0.32*1.88973/2 */
#define MAX_STDC 2.19208680f   /* 2.32*1.88973/2 */
#define PI_F     3.14159265358979f
#define LOG2E_F  1.44269504089f

static __device__ __forceinline__ float silu_f(float x) {
  return x / (1.0f + __expf(-x));
}

// ---------------------------------------------------------------------------
// K1 (unchanged): weights staged through LDS once per block. 256 blocks.
// ---------------------------------------------------------------------------
__global__ __launch_bounds__(256) void k_pre(const float* __restrict__ h,
    const float* __restrict__ W_pre, const float* __restrict__ b_pre,
    const float* __restrict__ W_down, const float* __restrict__ gw,
    float* __restrict__ hdg4) {
  __shared__ float bigW[12288];
  __shared__ float h_t[8 * INNF];
  __shared__ float hp_t[8 * H];
  int t = threadIdx.x;
  int n0 = blockIdx.x * 8;
  int lw = t & 31;
  int g  = t >> 5;
  int w0 = lw * 4;

  #pragma unroll
  for (int i = 0; i < 2; ++i) {
    int idx = t + i * 256;
    int row = idx >> 6, col = (idx & 63) << 2;
    *(float4*)&h_t[row * INNF + col] =
        *(const float4*)(h + (size_t)(n0 + row) * INNF + col);
  }

  float acc[4] = {};
  for (int kc = 0; kc < 256; kc += 64) {
    __syncthreads();
    #pragma unroll
    for (int i = 0; i < 8; ++i) {
      int idx = t + i * 256;
      *(float4*)&bigW[idx * 4] = *(const float4*)(W_pre + (size_t)kc * H + idx * 4);
    }
    __syncthreads();
    #pragma unroll 4
    for (int u4 = 0; u4 < 16; ++u4) {
      float4 hv = *(const float4*)&h_t[g * INNF + kc + u4 * 4];
      float hvv[4] = {hv.x, hv.y, hv.z, hv.w};
      #pragma unroll
      for (int uu = 0; uu < 4; ++uu) {
        float4 wv = *(const float4*)&bigW[(u4 * 4 + uu) * H + w0];
        acc[0] += hvv[uu] * wv.x; acc[1] += hvv[uu] * wv.y;
        acc[2] += hvv[uu] * wv.z; acc[3] += hvv[uu] * wv.w;
      }
    }
  }
  {
    float4 bv = *(const float4*)(b_pre + w0);
    float4 o = make_float4(silu_f(acc[0] + bv.x), silu_f(acc[1] + bv.y),
                           silu_f(acc[2] + bv.z), silu_f(acc[3] + bv.w));
    __syncthreads();
    *(float4*)&hp_t[g * H + w0] = o;
  }

  float acc2[3][4] = {};
  for (int kc = 0; kc < 128; kc += 32) {
    __syncthreads();
    #pragma unroll
    for (int i = 0; i < 12; ++i) {
      int idx = t + i * 256;
      int l = idx >> 10, r4 = idx & 1023;
      *(float4*)&bigW[idx * 4] =
          *(const float4*)(W_down + ((size_t)l * H + kc) * H + r4 * 4);
    }
    __syncthreads();
    #pragma unroll 2
    for (int u4 = 0; u4 < 8; ++u4) {
      float4 pv = *(const float4*)&hp_t[g * H + kc + u4 * 4];
      float pvv[4] = {pv.x, pv.y, pv.z, pv.w};
      #pragma unroll
      for (int uu = 0; uu < 4; ++uu) {
        int ul = u4 * 4 + uu;
        #pragma unroll
        for (int l = 0; l < 3; ++l) {
          float4 wv = *(const float4*)&bigW[(l * 32 + ul) * H + w0];
          acc2[l][0] += pvv[uu] * wv.x; acc2[l][1] += pvv[uu] * wv.y;
          acc2[l][2] += pvv[uu] * wv.z; acc2[l][3] += pvv[uu] * wv.w;
        }
      }
    }
  }

  {
    const float stp = (MAX_STDC - MIN_STDC) / 127.0f;
    const float invn1 = 0.57735026919f, invn2 = 0.44721359550f;
    int n = n0 + g;
    float gwv = gw[n];
    #pragma unroll
    for (int i = 0; i < 4; ++i) {
      int w = w0 + i;
      float s = MIN_STDC + (float)w * stp;
      float temps = 2.0f * s * s;
      float coef = (2.0f / 3.0f) / (temps * powf(PI_F * temps, 1.5f));
      float sc = gwv * coef;
      *(float4*)(hdg4 + ((size_t)n * H + w) * 4) =
          make_float4(acc2[0][i] * sc, acc2[1][i] * sc * invn1,
                      acc2[2][i] * sc * invn2, 0.0f);
    }
  }
}

// ---------------------------------------------------------------------------
// K2 v4: pair loop, 128 n per block (16 s-slices, halves c_part traffic).
// 2 w per lane; 4 waves each own a private 32-n subchunk; 2-stage LDS tree
// reduce. grid (32 mg, 16 s) = 512 blocks, 60 KB LDS -> 2 blocks/CU.
// ---------------------------------------------------------------------------
__global__ __launch_bounds__(256) void k_down(const float* __restrict__ gc,
    const float* __restrict__ cc, const float* __restrict__ hdg4,
    float* __restrict__ c_part) {
  __shared__ float sh_t[6144];    // [n_loc 0..127][m_loc 0..3][12]
  __shared__ float red[9216];     // 2 x 4608 tree-reduce buffers
  int t = threadIdx.x;
  int m0 = blockIdx.x * 4;
  int ss = blockIdx.y;            // 0..15
  int n0 = ss * 128;
  int wv = t >> 6;
  int ln = t & 63;
  int w0 = ln * 2;

  // phase 0: SH tile (128n x 4m) = 512 pairs, 2 per thread
  #pragma unroll
  for (int i = 0; i < 2; ++i) {
    int idx = t + i * 256;
    int n_loc = idx >> 2, m_loc = idx & 3;
    int n = n0 + n_loc, m = m0 + m_loc;
    float dx = gc[3*n]   - cc[3*m];
    float dy = gc[3*n+1] - cc[3*m+1];
    float dz = gc[3*n+2] - cc[3*m+2];
    float d2 = dx*dx + dy*dy + dz*dz + 3e-20f;
    float inv = rsqrtf(d2);
    float x = dx*inv, y = dy*inv, z = dz*inv;
    const float s3 = 1.73205080757f;
    float* dst = &sh_t[(size_t)idx * 12];
    dst[0] = 1.0f; dst[1] = x; dst[2] = y; dst[3] = z;
    dst[4] = s3*x*z; dst[5] = s3*x*y; dst[6] = y*y - 0.5f*(x*x + z*z);
    dst[7] = s3*y*z; dst[8] = 0.5f*s3*(z*z - x*x);
    dst[9] = d2; dst[10] = 0.0f; dst[11] = 0.0f;
  }
  __syncthreads();

  const float stp = (MAX_STDC - MIN_STDC) / 127.0f;
  float sA = MIN_STDC + (float)w0 * stp;
  float sB = MIN_STDC + (float)(w0 + 1) * stp;
  float cA = -LOG2E_F / (2.0f * sA * sA);
  float cB = -LOG2E_F / (2.0f * sB * sB);

  float acc[4][9][2] = {};
  for (int j = 0; j < 32; ++j) {
    int nl = wv * 32 + j;
    const float4* hb = (const float4*)(hdg4 + ((size_t)(n0 + nl) * H + w0) * 4);
    float4 hv0 = hb[0];
    float4 hv1 = hb[1];
    const float* shb = &sh_t[(size_t)nl * 48];
    #pragma unroll
    for (int mm = 0; mm < 4; ++mm) {
      float4 q0 = *(const float4*)(shb + mm*12);
      float4 q1 = *(const float4*)(shb + mm*12 + 4);
      float4 q2 = *(const float4*)(shb + mm*12 + 8);
      float e0 = exp2f(q2.y * cA);
      float e1 = exp2f(q2.y * cB);
      float rp0 = e0 * q2.y, rp1 = e1 * q2.y;
      float a00 = hv0.x*rp0, a01 = hv0.y*rp0, a02 = hv0.z*rp0;
      float a10 = hv1.x*rp1, a11 = hv1.y*rp1, a12 = hv1.z*rp1;
      acc[mm][0][0] += a00;        acc[mm][0][1] += a10;
      acc[mm][1][0] += a01*q0.y;   acc[mm][1][1] += a11*q0.y;
      acc[mm][2][0] += a01*q0.z;   acc[mm][2][1] += a11*q0.z;
      acc[mm][3][0] += a01*q0.w;   acc[mm][3][1] += a11*q0.w;
      acc[mm][4][0] += a02*q1.x;   acc[mm][4][1] += a12*q1.x;
      acc[mm][5][0] += a02*q1.y;   acc[mm][5][1] += a12*q1.y;
      acc[mm][6][0] += a02*q1.z;   acc[mm][6][1] += a12*q1.z;
      acc[mm][7][0] += a02*q1.w;   acc[mm][7][1] += a12*q1.w;
      acc[mm][8][0] += a02*q2.x;   acc[mm][8][1] += a12*q2.x;
    }
  }

  __syncthreads();
  if (wv & 1) {
    float* dst = &red[(wv >> 1) * 4608];
    #pragma unroll
    for (int mm = 0; mm < 4; ++mm)
      #pragma unroll
      for (int li = 0; li < 9; ++li)
        *(float2*)&dst[(mm*9 + li)*128 + w0] =
            make_float2(acc[mm][li][0], acc[mm][li][1]);
  }
  __syncthreads();
  if (!(wv & 1)) {
    const float* src = &red[(wv >> 1) * 4608];
    #pragma unroll
    for (int mm = 0; mm < 4; ++mm)
      #pragma unroll
      for (int li = 0; li < 9; ++li) {
        float2 v = *(const float2*)&src[(mm*9 + li)*128 + w0];
        acc[mm][li][0] += v.x; acc[mm][li][1] += v.y;
      }
  }
  __syncthreads();
  if (wv == 2) {
    #pragma unroll
    for (int mm = 0; mm < 4; ++mm)
      #pragma unroll
      for (int li = 0; li < 9; ++li)
        *(float2*)&red[(mm*9 + li)*128 + w0] =
            make_float2(acc[mm][li][0], acc[mm][li][1]);
  }
  __syncthreads();
  if (wv == 0) {
    #pragma unroll
    for (int mm = 0; mm < 4; ++mm)
      #pragma unroll
      for (int li = 0; li < 9; ++li) {
        float2 v = *(const float2*)&red[(mm*9 + li)*128 + w0];
        float2 o = make_float2(acc[mm][li][0] + v.x, acc[mm][li][1] + v.y);
        *(float2*)&c_part[(((size_t)ss*M_PTS + m0 + mm)*9 + li)*H + w0] = o;
      }
  }
}

// ---------------------------------------------------------------------------
// K3: block = (m, li): sum 16 s-partials over u, contract with W_up.
// grid (128, 9) = 1152 blocks, 128 threads.
// ---------------------------------------------------------------------------
__global__ __launch_bounds__(128) void k_cu(const float* __restrict__ c_part,
    const float* __restrict__ W_up, float* __restrict__ CU9) {
  __shared__ float c_lds[H];
  int t = threadIdx.x;
  int m = blockIdx.x, li = blockIdx.y;
  float v = 0.0f;
  #pragma unroll
  for (int s = 0; s < 16; ++s)
    v += c_part[(((size_t)s*M_PTS + m)*9 + li)*H + t];
  c_lds[t] = v;
  __syncthreads();

  int l = (li == 0) ? 0 : (li < 4 ? 1 : 2);
  const float invn[3] = {1.0f, 0.57735026919f, 0.44721359550f};
  float acc = 0.0f;
  for (int u = 0; u < H; u += 4) {
    float w0 = W_up[((size_t)l*H + u + 0)*H + t];
    float w1 = W_up[((size_t)l*H + u + 1)*H + t];
    float w2 = W_up[((size_t)l*H + u + 2)*H + t];
    float w3 = W_up[((size_t)l*H + u + 3)*H + t];
    acc += c_lds[u]*w0 + c_lds[u+1]*w1 + c_lds[u+2]*w2 + c_lds[u+3]*w3;
  }
  CU9[((size_t)m*9 + li)*H + t] = acc * invn[l];
}

// ---------------------------------------------------------------------------
// K4 (reverted to R10): split-K 8 (16 m's per block, two 72-K chunks).
// Block tile 32n x 128w, thread tile 4n x 4w; grid (64, 8) = 512 blocks.
// ---------------------------------------------------------------------------
__global__ __launch_bounds__(256) void k_up(const float* __restrict__ gc,
    const float* __restrict__ cc, const float* __restrict__ CU9,
    float* __restrict__ out_part) {
  __shared__ float At[72 * 36];   // [mrel*9+li][n_loc 0..31]
  __shared__ float Bl[72 * 128];  // [k][w]
  int t = threadIdx.x;
  int n0 = blockIdx.x * 32;
  int ks = blockIdx.y;            // 0..7
  int wq  = t & 31;               // w0 = 4*wq
  int tgn = t >> 5;               // 0..7, n_loc0 = 4*tgn
  int w0 = wq * 4;
  float acc[4][4] = {};

  for (int ch = 0; ch < 2; ++ch) {
    int m0 = ks*16 + ch*8;
    if (ch) __syncthreads();
    {
      int n_loc = t >> 3, mrel = t & 7;
      int n = n0 + n_loc, m = m0 + mrel;
      float dx = gc[3*n]   - cc[3*m];
      float dy = gc[3*n+1] - cc[3*m+1];
      float dz = gc[3*n+2] - cc[3*m+2];
      float d2 = dx*dx + dy*dy + dz*dz + 3e-20f;
      float inv = rsqrtf(d2);
      float x = dx*inv, y = dy*inv, z = dz*inv;
      const float s3 = 1.73205080757f;
      float sh[9];
      sh[0] = 1.0f; sh[1] = x; sh[2] = y; sh[3] = z;
      sh[4] = s3*x*z; sh[5] = s3*x*y; sh[6] = y*y - 0.5f*(x*x + z*z);
      sh[7] = s3*y*z; sh[8] = 0.5f*s3*(z*z - x*x);
      #pragma unroll
      for (int li = 0; li < 9; ++li)
        At[(mrel*9 + li)*36 + n_loc] = sh[li];
    }
    #pragma unroll
    for (int i = 0; i < 9; ++i) {
      int idx = t + i*256;
      *(float4*)&Bl[idx*4] = *(const float4*)(CU9 + (size_t)m0*9*H + idx*4);
    }
    __syncthreads();

    #pragma unroll 8
    for (int k = 0; k < 72; ++k) {
      float4 a = *(const float4*)&At[k*36 + 4*tgn];
      float4 b = *(const float4*)&Bl[k*128 + w0];
      float av[4] = {a.x, a.y, a.z, a.w};
      float bv[4] = {b.x, b.y, b.z, b.w};
      #pragma unroll
      for (int r = 0; r < 4; ++r)
        #pragma unroll
        for (int c = 0; c < 4; ++c)
          acc[r][c] += av[r] * bv[c];
    }
  }
  #pragma unroll
  for (int r = 0; r < 4; ++r) {
    size_t row = (size_t)ks*N_PTS + n0 + 4*tgn + r;
    *(float4*)(out_part + row*H + w0) =
        make_float4(acc[r][0], acc[r][1], acc[r][2], acc[r][3]);
  }
}

// ---------------------------------------------------------------------------
// K5: reduce 8 split-K partials, post-MLP + silu -> d_out.
// ---------------------------------------------------------------------------
__global__ __launch_bounds__(256) void k_post(const float* __restrict__ out_part,
    const float* __restrict__ W_post, const float* __restrict__ b_post,
    float* __restrict__ out) {
  __shared__ float op[4 * H];
  int t = threadIdx.x;
  int n0 = blockIdx.x * 4;
  int w = t & 127, nh = t >> 7;

  #pragma unroll
  for (int i = 0; i < 2; ++i) {
    int idx = t + i*256;
    int nl = idx >> 7, ww = idx & 127;
    float v = 0.0f;
    #pragma unroll
    for (int s = 0; s < 8; ++s)
      v += out_part[((size_t)s*N_PTS + n0 + nl)*H + ww];
    op[nl*H + ww] = v;
  }
  __syncthreads();

  float acc[2] = {0.0f, 0.0f};
  for (int u = 0; u < H; u += 4) {
    float4 p0 = *(const float4*)&op[(nh*2 + 0)*H + u];
    float4 p1 = *(const float4*)&op[(nh*2 + 1)*H + u];
    float w0 = W_post[(u+0)*H + w];
    float w1 = W_post[(u+1)*H + w];
    float w2 = W_post[(u+2)*H + w];
    float w3 = W_post[(u+3)*H + w];
    acc[0] += p0.x*w0 + p0.y*w1 + p0.z*w2 + p0.w*w3;
    acc[1] += p1.x*w0 + p1.y*w1 + p1.z*w2 + p1.w*w3;
  }
  float bp = b_post[w];
  out[(size_t)(n0 + nh*2 + 0)*H + w] = silu_f(acc[0] + bp);
  out[(size_t)(n0 + nh*2 + 1)*H + w] = silu_f(acc[1] + bp);
}

// ---------------------------------------------------------------------------
extern "C" void kernel_launch(void* const* d_in, const int* in_sizes, int n_in,
                              void* d_out, int out_size, void* d_ws, size_t ws_size,
                              hipStream_t stream) {
  const float* h      = (const float*)d_in[0];
  const float* gc     = (const float*)d_in[1];
  const float* cc     = (const float*)d_in[2];
  const float* gw     = (const float*)d_in[3];
  const float* W_pre  = (const float*)d_in[4];
  const float* b_pre  = (const float*)d_in[5];
  const float* W_down = (const float*)d_in[6];
  const float* W_up   = (const float*)d_in[7];
  const float* W_post = (const float*)d_in[8];
  const float* b_post = (const float*)d_in[9];

  float* ws       = (float*)d_ws;
  float* hdg4     = ws;                     // 2048*128*4   = 1,048,576 f
  float* c_part   = hdg4 + 1048576;         // 16*128*9*128 = 2,359,296 f
  float* CU9      = c_part + 2359296;       // 128*9*128    =   147,456 f
  float* out_part = c_part;                 // 8*2048*128 = 2,097,152 f aliases
  float* out      = (float*)d_out;

  k_pre <<<256,           256, 0, stream>>>(h, W_pre, b_pre, W_down, gw, hdg4);
  k_down<<<dim3(32,16),   256, 0, stream>>>(gc, cc, hdg4, c_part);
  k_cu  <<<dim3(128,9),   128, 0, stream>>>(c_part, W_up, CU9);
  k_up  <<<dim3(64,8),    256, 0, stream>>>(gc, cc, CU9, out_part);
  k_post<<<512,           256, 0, stream>>>(out_part, W_post, b_post, out);
}